// Round 1
// baseline (1687.752 us; speedup 1.0000x reference)
//
#include <hip/hip_runtime.h>
#include <hip/hip_bf16.h>
#include <math.h>

#define MARGIN 0.3f
#define NCHUNK 8

// ---------------- Kernel 1: L2-normalize rows + family lookup ----------------
// One 64-lane wave per row (D == 64). 4 rows per 256-thread block.
__global__ __launch_bounds__(256) void norm_fam_kernel(const float* __restrict__ emb,
                                                       const int* __restrict__ labels,
                                                       float* __restrict__ embN,
                                                       int* __restrict__ fam, int B) {
    int lane = threadIdx.x & 63;
    int wid  = threadIdx.x >> 6;
    int row  = blockIdx.x * 4 + wid;
    if (row >= B) return;
    float v = emb[row * 64 + lane];
    float ss = v * v;
#pragma unroll
    for (int o = 32; o > 0; o >>= 1) ss += __shfl_xor(ss, o, 64);
    float n = fmaxf(sqrtf(ss), 1e-12f);
    embN[row * 64 + lane] = v / n;
    if (lane == 0) {
        const int table[6] = {0, 1, 2, 1, 3, 3};
        fam[row] = table[labels[row]];
    }
}

// ---------------- Kernel 2: fused GEMM + masked min/max ----------------
// Each block: 64 rows (i-tile) x one j-chunk of B/NCHUNK columns.
// 256 threads = 16x16, each computing a 4x4 micro-tile of dots.
// LDS tiles stored transposed [k][row] with stride 68 (16B-aligned float4 rows).
__global__ __launch_bounds__(256) void tile_kernel(const float* __restrict__ embN,
                                                   const int* __restrict__ fam,
                                                   float* __restrict__ pMinS,
                                                   float* __restrict__ pMaxD,
                                                   int B) {
    __shared__ float As[64][68];
    __shared__ float Bs[64][68];

    const int tid = threadIdx.x;
    const int tx = tid & 15;        // j sub-tile (4 cols each)
    const int ty = tid >> 4;        // i sub-tile (4 rows each)
    const int gi0 = blockIdx.x * 64;
    const int jPerChunk = B / NCHUNK;
    const int gjStart = blockIdx.y * jPerChunk;
    const int nJT = jPerChunk / 64;

    // Stage A tile (transposed): As[k][r] = embN[(gi0+r)*64 + k]
    for (int idx = tid; idx < 64 * 64; idx += 256) {
        int r = idx >> 6, k = idx & 63;
        As[k][r] = embN[(gi0 + r) * 64 + k];
    }

    int famI[4];
#pragma unroll
    for (int m = 0; m < 4; m++) famI[m] = fam[gi0 + ty * 4 + m];

    float minS[4] = {1e30f, 1e30f, 1e30f, 1e30f};
    float maxD[4] = {-1e30f, -1e30f, -1e30f, -1e30f};

    for (int jt = 0; jt < nJT; jt++) {
        const int gj0 = gjStart + jt * 64;
        __syncthreads();  // prior Bs reads done
        for (int idx = tid; idx < 64 * 64; idx += 256) {
            int r = idx >> 6, k = idx & 63;
            Bs[k][r] = embN[(gj0 + r) * 64 + k];
        }
        __syncthreads();

        float acc00 = 0.f, acc01 = 0.f, acc02 = 0.f, acc03 = 0.f;
        float acc10 = 0.f, acc11 = 0.f, acc12 = 0.f, acc13 = 0.f;
        float acc20 = 0.f, acc21 = 0.f, acc22 = 0.f, acc23 = 0.f;
        float acc30 = 0.f, acc31 = 0.f, acc32 = 0.f, acc33 = 0.f;

#pragma unroll
        for (int k = 0; k < 64; k++) {
            float4 a = *reinterpret_cast<const float4*>(&As[k][ty * 4]);
            float4 b = *reinterpret_cast<const float4*>(&Bs[k][tx * 4]);
            acc00 = fmaf(a.x, b.x, acc00);
            acc01 = fmaf(a.x, b.y, acc01);
            acc02 = fmaf(a.x, b.z, acc02);
            acc03 = fmaf(a.x, b.w, acc03);
            acc10 = fmaf(a.y, b.x, acc10);
            acc11 = fmaf(a.y, b.y, acc11);
            acc12 = fmaf(a.y, b.z, acc12);
            acc13 = fmaf(a.y, b.w, acc13);
            acc20 = fmaf(a.z, b.x, acc20);
            acc21 = fmaf(a.z, b.y, acc21);
            acc22 = fmaf(a.z, b.z, acc22);
            acc23 = fmaf(a.z, b.w, acc23);
            acc30 = fmaf(a.w, b.x, acc30);
            acc31 = fmaf(a.w, b.y, acc31);
            acc32 = fmaf(a.w, b.z, acc32);
            acc33 = fmaf(a.w, b.w, acc33);
        }

        int famJ[4];
#pragma unroll
        for (int n = 0; n < 4; n++) famJ[n] = fam[gj0 + tx * 4 + n];

        float accs[4][4] = {{acc00, acc01, acc02, acc03},
                            {acc10, acc11, acc12, acc13},
                            {acc20, acc21, acc22, acc23},
                            {acc30, acc31, acc32, acc33}};
#pragma unroll
        for (int m = 0; m < 4; m++) {
            int gi = gi0 + ty * 4 + m;
#pragma unroll
            for (int n = 0; n < 4; n++) {
                int gj = gj0 + tx * 4 + n;
                float d = accs[m][n];
                bool sameF = (famI[m] == famJ[n]);
                if (sameF && gi != gj) minS[m] = fminf(minS[m], d);
                if (!sameF)            maxD[m] = fmaxf(maxD[m], d);
            }
        }
    }

    // Reduce across the 16 threads (same ty) holding this row's column slices.
    // These are 16 consecutive, 16-aligned lanes within one wave.
#pragma unroll
    for (int m = 0; m < 4; m++) {
#pragma unroll
        for (int o = 8; o > 0; o >>= 1) {
            minS[m] = fminf(minS[m], __shfl_xor(minS[m], o, 64));
            maxD[m] = fmaxf(maxD[m], __shfl_xor(maxD[m], o, 64));
        }
    }
    if (tx == 0) {
#pragma unroll
        for (int m = 0; m < 4; m++) {
            int gi = gi0 + ty * 4 + m;
            pMinS[blockIdx.y * B + gi] = minS[m];
            pMaxD[blockIdx.y * B + gi] = maxD[m];
        }
    }
}

// ---------------- Kernel 3: reduce chunks, compute loss ----------------
__global__ __launch_bounds__(1024) void finalize_kernel(const float* __restrict__ pMinS,
                                                        const float* __restrict__ pMaxD,
                                                        float* __restrict__ out, int B) {
    float sum = 0.f, cnt = 0.f;
    for (int i = threadIdx.x; i < B; i += 1024) {
        float mn = 1e30f, mx = -1e30f;
#pragma unroll
        for (int c = 0; c < NCHUNK; c++) {
            mn = fminf(mn, pMinS[c * B + i]);
            mx = fmaxf(mx, pMaxD[c * B + i]);
        }
        if (mn < 1e29f && mx > -1e29f) {  // valid: has same && has diff
            float v = mx - mn + MARGIN;   // = d_pos - d_neg + margin
            sum += fmaxf(v, 0.f);
            cnt += 1.f;
        }
    }
#pragma unroll
    for (int o = 32; o > 0; o >>= 1) {
        sum += __shfl_xor(sum, o, 64);
        cnt += __shfl_xor(cnt, o, 64);
    }
    __shared__ float sS[16], sC[16];
    int lane = threadIdx.x & 63, w = threadIdx.x >> 6;
    if (lane == 0) { sS[w] = sum; sC[w] = cnt; }
    __syncthreads();
    if (threadIdx.x == 0) {
        float S = 0.f, C = 0.f;
        for (int i = 0; i < 16; i++) { S += sS[i]; C += sC[i]; }
        out[0] = S / fmaxf(C, 1.f);
    }
}

extern "C" void kernel_launch(void* const* d_in, const int* in_sizes, int n_in,
                              void* d_out, int out_size, void* d_ws, size_t ws_size,
                              hipStream_t stream) {
    const float* emb    = (const float*)d_in[0];
    const int*   labels = (const int*)d_in[1];
    const int B = in_sizes[1];  // 8192 (D == 64 assumed/fixed by problem)

    float* wsf   = (float*)d_ws;
    float* embN  = wsf;                                   // B*64 floats
    int*   fam   = (int*)(wsf + (size_t)B * 64);          // B ints
    float* pMinS = wsf + (size_t)B * 64 + B;              // NCHUNK*B floats
    float* pMaxD = pMinS + (size_t)NCHUNK * B;            // NCHUNK*B floats

    norm_fam_kernel<<<B / 4, 256, 0, stream>>>(emb, labels, embN, fam, B);
    dim3 grid(B / 64, NCHUNK);
    tile_kernel<<<grid, 256, 0, stream>>>(embN, fam, pMinS, pMaxD, B);
    finalize_kernel<<<1, 1024, 0, stream>>>(pMinS, pMaxD, (float*)d_out, B);
}

// Round 2
// 66.312 us; speedup vs baseline: 25.4515x; 25.4515x over previous
//
#include <hip/hip_runtime.h>
#include <math.h>

#define MARGIN 0.3f
#define NJ 32   // column chunks (grid.y)

typedef short bf16x8 __attribute__((ext_vector_type(8)));
typedef float f32x4 __attribute__((ext_vector_type(4)));

__device__ __forceinline__ unsigned short f2bf_rne(float x) {
    unsigned b = __float_as_uint(x);
    unsigned r = b + 0x7FFFu + ((b >> 16) & 1u);
    return (unsigned short)(r >> 16);
}
__device__ __forceinline__ float bf2f(unsigned short h) {
    return __uint_as_float(((unsigned)h) << 16);
}
// family table {0,1,2,1,3,3} packed 2 bits/entry
__device__ __forceinline__ int fam_of(int lbl) { return (0xF64 >> (2 * lbl)) & 3; }

// ---------------- K1: deterministic counting sort by family ----------------
// 1 block, 1024 threads, 8 rows/thread. Outputs posOf[row], famSorted[pos],
// famLoHi[f] = range [lo,hi) of family f in sorted order.
__global__ __launch_bounds__(1024) void sort_kernel(const int* __restrict__ labels,
                                                    int* __restrict__ posOf,
                                                    unsigned char* __restrict__ famSorted,
                                                    int* __restrict__ famLoHi, int B) {
    __shared__ int scan[1024][4];
    const int t = threadIdx.x;
    int lc[4] = {0, 0, 0, 0};
    int lf[8], lr[8];
#pragma unroll
    for (int j = 0; j < 8; j++) {
        int f = fam_of(labels[t * 8 + j]);
        lf[j] = f; lr[j] = lc[f]++;
    }
#pragma unroll
    for (int f = 0; f < 4; f++) scan[t][f] = lc[f];
    __syncthreads();
    for (int off = 1; off < 1024; off <<= 1) {
        int v0 = 0, v1 = 0, v2 = 0, v3 = 0;
        if (t >= off) { v0 = scan[t - off][0]; v1 = scan[t - off][1]; v2 = scan[t - off][2]; v3 = scan[t - off][3]; }
        __syncthreads();
        if (t >= off) { scan[t][0] += v0; scan[t][1] += v1; scan[t][2] += v2; scan[t][3] += v3; }
        __syncthreads();
    }
    int tot[4], base[4];
#pragma unroll
    for (int f = 0; f < 4; f++) tot[f] = scan[1023][f];
    base[0] = 0; base[1] = tot[0]; base[2] = base[1] + tot[1]; base[3] = base[2] + tot[2];
    int excl[4];
#pragma unroll
    for (int f = 0; f < 4; f++) excl[f] = base[f] + scan[t][f] - lc[f];
#pragma unroll
    for (int j = 0; j < 8; j++) {
        int pos = excl[lf[j]] + lr[j];
        posOf[t * 8 + j] = pos;
        famSorted[pos] = (unsigned char)lf[j];
    }
    if (t < 4) { famLoHi[t] = base[t]; famLoHi[4 + t] = base[t] + tot[t]; }
}

// ---------------- K2: normalize + bf16 hi/lo split + packed scatter ----------------
// Wave per row. pack layout (bf16 elems): idx = strip*1024 + (k>>3)*128 + (pos&15)*8 + (k&7)
// so in K3, lane l reads its MFMA fragment as one coalesced 16B load at strip*1024 + l*8.
__global__ __launch_bounds__(256) void normpack_kernel(const float* __restrict__ emb,
                                                       const int* __restrict__ posOf,
                                                       short* __restrict__ packHi,
                                                       short* __restrict__ packLo, int B) {
    const int lane = threadIdx.x & 63;
    const int wid  = threadIdx.x >> 6;
    const int row  = blockIdx.x * 4 + wid;
    float x = emb[(size_t)row * 64 + lane];
    float ss = x * x;
#pragma unroll
    for (int o = 32; o > 0; o >>= 1) ss += __shfl_xor(ss, o, 64);
    float n = fmaxf(sqrtf(ss), 1e-12f);
    float v = x / n;
    unsigned short h = f2bf_rne(v);
    float lo = v - bf2f(h);
    unsigned short l = f2bf_rne(lo);
    int pos = posOf[row];
    size_t idx = (size_t)(pos >> 4) * 1024 + (size_t)(lane >> 3) * 128 + (size_t)(pos & 15) * 8 + (lane & 7);
    packHi[idx] = (short)h;
    packLo[idx] = (short)l;
}

// ---------------- K3: MFMA GEMM + masked min/max (no LDS) ----------------
// 4 waves/block, 64 rows/wave (4 strips of 16), chunk of B/NJ cols.
__global__ __launch_bounds__(256) void gemm_minmax_kernel(
    const short* __restrict__ packHi, const short* __restrict__ packLo,
    const unsigned char* __restrict__ famSorted, const int* __restrict__ famLoHi,
    float* __restrict__ pMin, float* __restrict__ pMax, int B) {
    const int lane = threadIdx.x & 63;
    const int wid  = threadIdx.x >> 6;
    const int g = lane >> 4;
    const int c = lane & 15;
    const int rowBase = blockIdx.x * 256 + wid * 64;
    const int aStrip0 = rowBase >> 4;

    // A fragments: 4 strips x 2 k-windows x (hi,lo). 64 VGPRs, resident all sweep.
    bf16x8 aHi[4][2], aLo[4][2];
#pragma unroll
    for (int s = 0; s < 4; s++) {
        const bf16x8* pH = (const bf16x8*)(packHi + (size_t)(aStrip0 + s) * 1024);
        const bf16x8* pL = (const bf16x8*)(packLo + (size_t)(aStrip0 + s) * 1024);
        aHi[s][0] = pH[lane]; aHi[s][1] = pH[64 + lane];
        aLo[s][0] = pL[lane]; aLo[s][1] = pL[64 + lane];
    }

    // Per-strip family classification (rows sorted -> piecewise constant).
    int sLo[4], sHi[4], sUni[4];
#pragma unroll
    for (int s = 0; s < 4; s++) {
        int f0  = famSorted[rowBase + s * 16];
        int f15 = famSorted[rowBase + s * 16 + 15];
        sUni[s] = __builtin_amdgcn_readfirstlane((f0 == f15) ? 1 : 0);
        sLo[s]  = __builtin_amdgcn_readfirstlane(famLoHi[f0]);
        sHi[s]  = __builtin_amdgcn_readfirstlane(famLoHi[4 + f0]);
    }

    f32x4 mn[4], mx[4];
#pragma unroll
    for (int s = 0; s < 4; s++)
#pragma unroll
        for (int r = 0; r < 4; r++) { mn[s][r] = 1e30f; mx[s][r] = -1e30f; }

    const int jChunk0 = blockIdx.y * (B / NJ);
    const int NJT = (B / NJ) >> 4;

    for (int jt = 0; jt < NJT; jt++) {
        const int j0 = jChunk0 + jt * 16;
        const int jStrip = j0 >> 4;
        const bf16x8* pBH = (const bf16x8*)(packHi + (size_t)jStrip * 1024);
        const bf16x8* pBL = (const bf16x8*)(packLo + (size_t)jStrip * 1024);
        bf16x8 bh0 = pBH[lane], bh1 = pBH[64 + lane];
        bf16x8 bl0 = pBL[lane], bl1 = pBL[64 + lane];

#pragma unroll
        for (int s = 0; s < 4; s++) {
            f32x4 acc = {0.f, 0.f, 0.f, 0.f};
            // bf16x2: hi*hi + lo*hi + hi*lo over two K=32 windows
            acc = __builtin_amdgcn_mfma_f32_16x16x32_bf16(aHi[s][0], bh0, acc, 0, 0, 0);
            acc = __builtin_amdgcn_mfma_f32_16x16x32_bf16(aHi[s][1], bh1, acc, 0, 0, 0);
            acc = __builtin_amdgcn_mfma_f32_16x16x32_bf16(aLo[s][0], bh0, acc, 0, 0, 0);
            acc = __builtin_amdgcn_mfma_f32_16x16x32_bf16(aLo[s][1], bh1, acc, 0, 0, 0);
            acc = __builtin_amdgcn_mfma_f32_16x16x32_bf16(aHi[s][0], bl0, acc, 0, 0, 0);
            acc = __builtin_amdgcn_mfma_f32_16x16x32_bf16(aHi[s][1], bl1, acc, 0, 0, 0);

            if (sUni[s] && j0 >= sLo[s] && j0 + 16 <= sHi[s]) {
                // tile fully same-family (diag dot==1 can never be the min)
#pragma unroll
                for (int r = 0; r < 4; r++) mn[s][r] = fminf(mn[s][r], acc[r]);
            } else if (sUni[s] && (j0 >= sHi[s] || j0 + 16 <= sLo[s])) {
                // tile fully different-family
#pragma unroll
                for (int r = 0; r < 4; r++) mx[s][r] = fmaxf(mx[s][r], acc[r]);
            } else {
                // boundary tile: per-element family compare
                int fj = famSorted[j0 + c];
                unsigned fi4 = *(const unsigned*)(famSorted + rowBase + s * 16 + g * 4);
#pragma unroll
                for (int r = 0; r < 4; r++) {
                    int fir = (int)((fi4 >> (8 * r)) & 255u);
                    bool same = (fir == fj);
                    float d = acc[r];
                    mn[s][r] = fminf(mn[s][r], same ? d : 1e30f);
                    mx[s][r] = fmaxf(mx[s][r], same ? -1e30f : d);
                }
            }
        }
    }

    // Reduce across the 16 column-lanes (same g), then write per-row partials.
#pragma unroll
    for (int s = 0; s < 4; s++)
#pragma unroll
        for (int r = 0; r < 4; r++) {
            float mnv = mn[s][r], mxv = mx[s][r];
#pragma unroll
            for (int o = 8; o > 0; o >>= 1) {
                mnv = fminf(mnv, __shfl_xor(mnv, o, 64));
                mxv = fmaxf(mxv, __shfl_xor(mxv, o, 64));
            }
            if (c == 0) {
                int row = rowBase + s * 16 + g * 4 + r;  // sorted-row index
                pMin[(size_t)blockIdx.y * B + row] = mnv;
                pMax[(size_t)blockIdx.y * B + row] = mxv;
            }
        }
}

// ---------------- K4: per-row chunk combine + block partial sums ----------------
__global__ __launch_bounds__(256) void rowloss_kernel(const float* __restrict__ pMin,
                                                      const float* __restrict__ pMax,
                                                      float* __restrict__ partial, int B) {
    const int row = blockIdx.x * 256 + threadIdx.x;
    float mn = 1e30f, mx = -1e30f;
#pragma unroll 4
    for (int cn = 0; cn < NJ; cn++) {
        mn = fminf(mn, pMin[(size_t)cn * B + row]);
        mx = fmaxf(mx, pMax[(size_t)cn * B + row]);
    }
    float sum = 0.f, cnt = 0.f;
    if (mn < 1e29f && mx > -1e29f) {  // has same && has diff
        sum = fmaxf(mx - mn + MARGIN, 0.f);  // relu(d_pos - d_neg + margin)
        cnt = 1.f;
    }
#pragma unroll
    for (int o = 32; o > 0; o >>= 1) {
        sum += __shfl_xor(sum, o, 64);
        cnt += __shfl_xor(cnt, o, 64);
    }
    __shared__ float sS[4], sC[4];
    const int lane = threadIdx.x & 63, w = threadIdx.x >> 6;
    if (lane == 0) { sS[w] = sum; sC[w] = cnt; }
    __syncthreads();
    if (threadIdx.x == 0) {
        partial[blockIdx.x]      = sS[0] + sS[1] + sS[2] + sS[3];
        partial[64 + blockIdx.x] = sC[0] + sC[1] + sC[2] + sC[3];
    }
}

// ---------------- K5: deterministic final reduce ----------------
__global__ void final_kernel(const float* __restrict__ partial, float* __restrict__ out, int nb) {
    if (threadIdx.x == 0) {
        float S = 0.f, C = 0.f;
        for (int i = 0; i < nb; i++) { S += partial[i]; C += partial[64 + i]; }
        out[0] = S / fmaxf(C, 1.f);
    }
}

extern "C" void kernel_launch(void* const* d_in, const int* in_sizes, int n_in,
                              void* d_out, int out_size, void* d_ws, size_t ws_size,
                              hipStream_t stream) {
    const float* emb    = (const float*)d_in[0];
    const int*   labels = (const int*)d_in[1];
    const int B = in_sizes[1];  // 8192, D == 64

    char* base = (char*)d_ws;
    size_t off = 0;
    auto alloc = [&](size_t bytes) -> char* {
        char* p = base + off;
        off = (off + bytes + 255) & ~(size_t)255;
        return p;
    };
    int*           posOf     = (int*)alloc((size_t)B * 4);
    unsigned char* famSorted = (unsigned char*)alloc((size_t)B);
    int*           famLoHi   = (int*)alloc(32);
    short*         packHi    = (short*)alloc((size_t)B * 64 * 2);
    short*         packLo    = (short*)alloc((size_t)B * 64 * 2);
    float*         pMin      = (float*)alloc((size_t)NJ * B * 4);
    float*         pMax      = (float*)alloc((size_t)NJ * B * 4);
    float*         partial   = (float*)alloc(128 * 4);

    sort_kernel<<<1, 1024, 0, stream>>>(labels, posOf, famSorted, famLoHi, B);
    normpack_kernel<<<B / 4, 256, 0, stream>>>(emb, posOf, packHi, packLo, B);
    dim3 g3(B / 256, NJ);
    gemm_minmax_kernel<<<g3, 256, 0, stream>>>(packHi, packLo, famSorted, famLoHi, pMin, pMax, B);
    rowloss_kernel<<<B / 256, 256, 0, stream>>>(pMin, pMax, partial, B);
    final_kernel<<<1, 64, 0, stream>>>(partial, (float*)d_out, B / 256);
}